// Round 1
// baseline (231.622 us; speedup 1.0000x reference)
//
#include <hip/hip_runtime.h>

// Problem constants (from reference setup_inputs)
constexpr int NA = 256;   // N_AGENTS
constexpr int B  = 64;    // BATCH
constexpr int S  = 20;    // SEQ
constexpr int H  = 128;   // HID

// One block per (agent i, batch b). 128 threads: thread t owns hidden channel t.
// Phase 1: stage this batch's 256 last-timestep positions in LDS.
// Phase 2: build compacted neighbor list (expected ~15 of 256) via LDS atomic.
// Phase 3: accumulate h_last[j,b,t] over neighbors (coalesced 512B rows, L2-resident),
//          divide by max(count,1).
// Numerics: mask must be bit-exact vs numpy fp32 -> __f*_rn intrinsics, no FMA
// contraction in dx*dx+dy*dy, correctly-rounded sqrt, inclusive <=.
__global__ __launch_bounds__(128, 4) void social_pool_kernel(
    const float* __restrict__ h,    // (NA, B, S, H)
    const float* __restrict__ p,    // (NA, B, S, 2)
    const float* __restrict__ rptr, // scalar radius
    float* __restrict__ out)        // (NA, B, H)
{
    const int i   = blockIdx.x & (NA - 1);
    const int b   = blockIdx.x >> 8;
    const int tid = threadIdx.x;

    __shared__ float px[NA];
    __shared__ float py[NA];
    __shared__ int   nbr[NA];
    __shared__ int   cnt;
    if (tid == 0) cnt = 0;

    // Phase 1: positions of all agents in this batch, last timestep.
    for (int j = tid; j < NA; j += 128) {
        const float2 pj = *(const float2*)(p + (((size_t)(j * B + b)) * S + (S - 1)) * 2);
        px[j] = pj.x;
        py[j] = pj.y;
    }
    __syncthreads();

    const float r  = *rptr;
    const float xi = px[i];
    const float yi = py[i];

    // Phase 2: compacted neighbor list. Order nondeterministic -> only ulp-level
    // reordering of the float sum (adding exact zeros is exact; fine vs 6.7e-2 thr).
    for (int j = tid; j < NA; j += 128) {
        const float dx   = __fsub_rn(xi, px[j]);
        const float dy   = __fsub_rn(yi, py[j]);
        const float d2   = __fadd_rn(__fmul_rn(dx, dx), __fmul_rn(dy, dy));
        const float dist = __fsqrt_rn(d2);
        if (dist <= r && j != i) {
            const int k = atomicAdd(&cnt, 1);
            nbr[k] = j;
        }
    }
    __syncthreads();
    const int n = cnt;

    // Phase 3: accumulate neighbor hidden rows.
    float acc = 0.0f;
    const size_t hbase = ((size_t)b * S + (S - 1)) * H + tid;
    const size_t jstride = (size_t)B * S * H;
    for (int k = 0; k < n; ++k) {
        const int j = nbr[k];
        acc += h[(size_t)j * jstride + hbase];
    }

    const float c = (float)(n > 0 ? n : 1);
    out[((size_t)i * B + b) * H + tid] = __fdiv_rn(acc, c);
}

extern "C" void kernel_launch(void* const* d_in, const int* in_sizes, int n_in,
                              void* d_out, int out_size, void* d_ws, size_t ws_size,
                              hipStream_t stream) {
    const float* h    = (const float*)d_in[0];
    const float* p    = (const float*)d_in[1];
    const float* rptr = (const float*)d_in[2];
    float* out        = (float*)d_out;

    (void)in_sizes; (void)n_in; (void)out_size; (void)d_ws; (void)ws_size;

    social_pool_kernel<<<dim3(NA * B), dim3(128), 0, stream>>>(h, p, rptr, out);
}

// Round 2
// 217.117 us; speedup vs baseline: 1.0668x; 1.0668x over previous
//
#include <hip/hip_runtime.h>

// Problem constants (from reference setup_inputs)
constexpr int NA = 256;   // N_AGENTS
constexpr int B  = 64;    // BATCH
constexpr int S  = 20;    // SEQ
constexpr int H  = 128;   // HID

constexpr int AGENTS_PER_BLOCK = 16;  // 4 waves x 4 agents each
constexpr int BLOCKS = (NA / AGENTS_PER_BLOCK) * B;  // 16 * 64 = 1024

// One block per (batch b, group of 16 agents). 256 threads = 4 waves.
// - Stage all 256 last-timestep positions for this batch in LDS (once per block,
//   16x less scattered-position traffic than the per-(i,b)-block version).
// - Each wave handles 4 agents independently (NO barriers after staging):
//   neighbor set built as four 64-bit __ballot masks (wave-uniform; no LDS atomic).
// - Gather: lane owns 2 channels (float2) -> one neighbor row = one coalesced
//   512B wave load. Interleaved extraction across the 4 mask words keeps up to
//   4 independent global loads in flight per iteration (vs 1 in the serial loop).
// Numerics: distance must be bit-exact vs numpy fp32 -> __f*_rn, no FMA
// contraction, correctly-rounded sqrt, inclusive <=; __fdiv_rn epilogue.
__global__ __launch_bounds__(256, 4) void social_pool_kernel(
    const float* __restrict__ h,    // (NA, B, S, H)
    const float* __restrict__ p,    // (NA, B, S, 2)
    const float* __restrict__ rptr, // scalar radius
    float* __restrict__ out)        // (NA, B, H)
{
    const int group = blockIdx.x & (NA / AGENTS_PER_BLOCK - 1);  // 0..15
    const int b     = blockIdx.x >> 4;                           // 0..63
    const int tid   = threadIdx.x;
    const int wave  = tid >> 6;   // 0..3
    const int lane  = tid & 63;

    __shared__ float px[NA];
    __shared__ float py[NA];

    // Stage this batch's 256 last-timestep positions (scattered 8B loads, L2-hit).
    {
        const int j = tid;  // 256 threads, 256 agents
        const float2 pj = *(const float2*)(p + (((size_t)(j * B + b)) * S + (S - 1)) * 2);
        px[j] = pj.x;
        py[j] = pj.y;
    }
    __syncthreads();

    const float r = *rptr;

    const size_t jstride = (size_t)B * S * H;
    const float* hb = h + ((size_t)b * S + (S - 1)) * H + 2 * lane;

    // Each wave processes 4 agents, fully independent (no barriers).
    for (int a = 0; a < 4; ++a) {
        const int i = group * AGENTS_PER_BLOCK + wave * 4 + a;
        const float xi = px[i];
        const float yi = py[i];

        // Build neighbor bitmask: four 64-bit words (wave-uniform after ballot).
        unsigned long long m[4];
        #pragma unroll
        for (int k = 0; k < 4; ++k) {
            const int j = (k << 6) + lane;
            const float dx   = __fsub_rn(xi, px[j]);
            const float dy   = __fsub_rn(yi, py[j]);
            const float d2   = __fadd_rn(__fmul_rn(dx, dx), __fmul_rn(dy, dy));
            const float dist = __fsqrt_rn(d2);
            m[k] = __ballot(dist <= r);
        }
        m[i >> 6] &= ~(1ull << (i & 63));  // exclude self

        const int n = __popcll(m[0]) + __popcll(m[1]) + __popcll(m[2]) + __popcll(m[3]);

        // Interleaved gather: up to 4 independent row loads in flight.
        float ax = 0.0f, ay = 0.0f;
        while (m[0] | m[1] | m[2] | m[3]) {
            float2 v[4];
            bool got[4];
            #pragma unroll
            for (int k = 0; k < 4; ++k) {
                got[k] = (m[k] != 0ull);
                if (got[k]) {
                    const int j = (k << 6) + __builtin_ctzll(m[k]);
                    m[k] &= m[k] - 1ull;
                    v[k] = *(const float2*)(hb + (size_t)j * jstride);
                }
            }
            #pragma unroll
            for (int k = 0; k < 4; ++k) {
                if (got[k]) { ax += v[k].x; ay += v[k].y; }
            }
        }

        const float c = (float)(n > 0 ? n : 1);
        float2 o;
        o.x = __fdiv_rn(ax, c);
        o.y = __fdiv_rn(ay, c);
        *(float2*)(out + ((size_t)i * B + b) * H + 2 * lane) = o;
    }
}

extern "C" void kernel_launch(void* const* d_in, const int* in_sizes, int n_in,
                              void* d_out, int out_size, void* d_ws, size_t ws_size,
                              hipStream_t stream) {
    const float* h    = (const float*)d_in[0];
    const float* p    = (const float*)d_in[1];
    const float* rptr = (const float*)d_in[2];
    float* out        = (float*)d_out;

    (void)in_sizes; (void)n_in; (void)out_size; (void)d_ws; (void)ws_size;

    social_pool_kernel<<<dim3(BLOCKS), dim3(256), 0, stream>>>(h, p, rptr, out);
}